// Round 2
// baseline (4039.788 us; speedup 1.0000x reference)
//
#include <hip/hip_runtime.h>
#include <math.h>

#define NK 27
#define C1 128
#define C2 14
#define X1S 16   // padded row stride for intermediate (64B aligned)

// conv1 for weight k = 26 - m, iterating the MIRROR map m:
//   gather feat[out_idx[m][j]]  (sequential: out_idx[m] is sorted, prefix-compacted)
//   scatter x1[in_idx[m][j]]    (random atomics, 56B rows)
__global__ __launch_bounds__(256) void conv1_kernel(
    const float* __restrict__ feat, const float* __restrict__ W1,
    const int* __restrict__ in_idx, const int* __restrict__ out_idx,
    float* __restrict__ x1, int N)
{
    const int m = blockIdx.x;          // map index (0..26)
    const int k = 26 - m;              // weight index
    const int* gidx = out_idx + (size_t)m * N;  // gather (sequential)
    const int* sidx = in_idx  + (size_t)m * N;  // scatter (random)

    const int jchunk = blockIdx.y * 1024;
    // prefix property: if first entry of this chunk is padded, all of it is.
    if (sidx[jchunk] >= N) return;     // block-uniform -> safe to skip barrier

    __shared__ float Wl[C2 * C1];      // transposed: Wl[c*128 + i] = W1[k][i][c]
    const int tid = threadIdx.x;
    for (int t = tid; t < C2 * C1; t += 256) {
        int c = t >> 7;
        int i = t & 127;
        Wl[t] = W1[k * (C1 * C2) + i * C2 + c];
    }
    __syncthreads();

    const int jbase = jchunk + tid * 4;
    if (jbase >= N) return;            // N % 4 == 0 -> int4 load safe below

    const int4 gi = *(const int4*)(gidx + jbase);
    const int4 si = *(const int4*)(sidx + jbase);
    int src[4] = { gi.x, gi.y, gi.z, gi.w };
    int dst[4] = { si.x, si.y, si.z, si.w };

    bool valid[4];
    bool any = false;
    #pragma unroll
    for (int p = 0; p < 4; ++p) {
        valid[p] = (dst[p] < N);
        any |= valid[p];
        if (!valid[p]) src[p] = 0;     // safe dummy row; result discarded
    }
    if (!any) return;

    const float4* fa = (const float4*)(feat + (size_t)src[0] * C1);
    const float4* fb = (const float4*)(feat + (size_t)src[1] * C1);
    const float4* fc = (const float4*)(feat + (size_t)src[2] * C1);
    const float4* fd = (const float4*)(feat + (size_t)src[3] * C1);

    float acc[4][C2];
    #pragma unroll
    for (int p = 0; p < 4; ++p)
        #pragma unroll
        for (int c = 0; c < C2; ++c) acc[p][c] = 0.f;

    for (int i4 = 0; i4 < C1 / 4; ++i4) {
        float4 a  = fa[i4];
        float4 b  = fb[i4];
        float4 cc = fc[i4];
        float4 d  = fd[i4];
        #pragma unroll
        for (int c = 0; c < C2; ++c) {
            float4 w = *(const float4*)&Wl[c * C1 + i4 * 4];
            acc[0][c] = fmaf(a.x,  w.x, fmaf(a.y,  w.y, fmaf(a.z,  w.z, fmaf(a.w,  w.w, acc[0][c]))));
            acc[1][c] = fmaf(b.x,  w.x, fmaf(b.y,  w.y, fmaf(b.z,  w.z, fmaf(b.w,  w.w, acc[1][c]))));
            acc[2][c] = fmaf(cc.x, w.x, fmaf(cc.y, w.y, fmaf(cc.z, w.z, fmaf(cc.w, w.w, acc[2][c]))));
            acc[3][c] = fmaf(d.x,  w.x, fmaf(d.y,  w.y, fmaf(d.z,  w.z, fmaf(d.w,  w.w, acc[3][c]))));
        }
    }

    #pragma unroll
    for (int p = 0; p < 4; ++p) {
        if (!valid[p]) continue;
        float* o = x1 + (size_t)dst[p] * X1S;
        #pragma unroll
        for (int c = 0; c < C2; ++c) atomicAdd(o + c, acc[p][c]);
    }
}

// exact GELU, in-place on x1 (padded lanes are 0 -> gelu(0)=0)
__global__ __launch_bounds__(256) void gelu_kernel(float* __restrict__ x, int total4)
{
    int i = blockIdx.x * 256 + threadIdx.x;
    if (i >= total4) return;
    float4 v = ((float4*)x)[i];
    v.x = 0.5f * v.x * (1.0f + erff(v.x * 0.70710678118654752f));
    v.y = 0.5f * v.y * (1.0f + erff(v.y * 0.70710678118654752f));
    v.z = 0.5f * v.z * (1.0f + erff(v.z * 0.70710678118654752f));
    v.w = 0.5f * v.w * (1.0f + erff(v.w * 0.70710678118654752f));
    ((float4*)x)[i] = v;
}

// conv2, same mirror trick: gather x1[out_idx[m][j]] sequential, scatter out[in_idx[m][j]]
__global__ __launch_bounds__(256) void conv2_kernel(
    const float* __restrict__ x1, const float* __restrict__ W2,
    const int* __restrict__ in_idx, const int* __restrict__ out_idx,
    float* __restrict__ out, int N)
{
    const int m = blockIdx.x;
    const int k = 26 - m;
    const int* gidx = out_idx + (size_t)m * N;
    const int* sidx = in_idx  + (size_t)m * N;

    const int jchunk = blockIdx.y * 512;
    if (sidx[jchunk] >= N) return;

    __shared__ float Wl[C2 * 16];      // transposed, padded: Wl[c*16 + i] = W2[k][i][c]
    const int tid = threadIdx.x;
    if (tid < C2 * C2) {
        int c = tid / C2;
        int i = tid % C2;
        Wl[c * 16 + i] = W2[k * (C2 * C2) + i * C2 + c];
    }
    __syncthreads();

    const int jbase = jchunk + tid * 2;
    if (jbase >= N) return;            // N % 2 == 0 -> int2 load safe

    const int2 gi = *(const int2*)(gidx + jbase);
    const int2 si = *(const int2*)(sidx + jbase);
    int src[2] = { gi.x, gi.y };
    int dst[2] = { si.x, si.y };
    bool valid[2] = { dst[0] < N, dst[1] < N };
    if (!valid[0] && !valid[1]) return;

    float f[2][C2];
    #pragma unroll
    for (int p = 0; p < 2; ++p) {
        if (valid[p]) {
            const float* r = x1 + (size_t)src[p] * X1S;
            float4 q0 = *(const float4*)(r + 0);
            float4 q1 = *(const float4*)(r + 4);
            float4 q2 = *(const float4*)(r + 8);
            float2 q3 = *(const float2*)(r + 12);
            f[p][0]=q0.x; f[p][1]=q0.y; f[p][2]=q0.z; f[p][3]=q0.w;
            f[p][4]=q1.x; f[p][5]=q1.y; f[p][6]=q1.z; f[p][7]=q1.w;
            f[p][8]=q2.x; f[p][9]=q2.y; f[p][10]=q2.z; f[p][11]=q2.w;
            f[p][12]=q3.x; f[p][13]=q3.y;
        } else {
            #pragma unroll
            for (int i = 0; i < C2; ++i) f[p][i] = 0.f;
        }
    }

    float acc[2][C2];
    #pragma unroll
    for (int c = 0; c < C2; ++c) {
        float s0 = 0.f, s1 = 0.f;
        #pragma unroll
        for (int i = 0; i < C2; ++i) {
            float w = Wl[c * 16 + i];
            s0 = fmaf(f[0][i], w, s0);
            s1 = fmaf(f[1][i], w, s1);
        }
        acc[0][c] = s0;
        acc[1][c] = s1;
    }

    #pragma unroll
    for (int p = 0; p < 2; ++p) {
        if (!valid[p]) continue;
        float* o = out + (size_t)dst[p] * C2;
        #pragma unroll
        for (int c = 0; c < C2; ++c) atomicAdd(o + c, acc[p][c]);
    }
}

extern "C" void kernel_launch(void* const* d_in, const int* in_sizes, int n_in,
                              void* d_out, int out_size, void* d_ws, size_t ws_size,
                              hipStream_t stream)
{
    const float* feat    = (const float*)d_in[0];
    const float* W1      = (const float*)d_in[1];
    const float* W2      = (const float*)d_in[2];
    const int*   in_idx  = (const int*)d_in[3];
    const int*   out_idx = (const int*)d_in[4];
    float*       out     = (float*)d_out;

    const int N = in_sizes[0] / C1;      // 400000

    float* x1 = (float*)d_ws;            // N x 16 fp32 = 25.6 MB

    hipMemsetAsync(x1, 0, (size_t)N * X1S * sizeof(float), stream);
    hipMemsetAsync(out, 0, (size_t)out_size * sizeof(float), stream);

    {
        dim3 grid(NK, (N + 1023) / 1024);   // k fastest -> 27 sweeps in lockstep
        conv1_kernel<<<grid, 256, 0, stream>>>(feat, W1, in_idx, out_idx, x1, N);
    }
    {
        int total4 = N * X1S / 4;
        gelu_kernel<<<(total4 + 255) / 256, 256, 0, stream>>>(x1, total4);
    }
    {
        dim3 grid(NK, (N + 511) / 512);
        conv2_kernel<<<grid, 256, 0, stream>>>(x1, W2, in_idx, out_idx, out, N);
    }
}

// Round 3
// 996.558 us; speedup vs baseline: 4.0537x; 4.0537x over previous
//
#include <hip/hip_runtime.h>
#include <math.h>

#define NK 27
#define C1 128
#define C2 14
#define X1S 16        // padded row stride for intermediate (64B)
#define PROW 16       // P row stride in floats (64B)
#define CAP 131072    // per-sparse-map pair capacity (actual ~76k, huge margin)
#define WIN 1024      // dst-address window per phase-A block

// ---------- setup: per-(map,window) j-ranges via binary search ----------
__global__ __launch_bounds__(256) void ranges_kernel(
    const int* __restrict__ out_idx, int* __restrict__ r, int N, int nwin)
{
    int t = blockIdx.x * 256 + threadIdx.x;
    int total = NK * (nwin + 1);
    if (t >= total) return;
    int mm = t / (nwin + 1);
    int b  = t % (nwin + 1);
    long tgt_l = (long)b * WIN; if (tgt_l > N) tgt_l = N;
    int target = (int)tgt_l;
    const int* a = out_idx + (size_t)mm * N;
    int lo = 0, hi = N;
    while (lo < hi) { int mid = (lo + hi) >> 1; if (a[mid] < target) lo = mid + 1; else hi = mid; }
    r[t] = lo;   // lower_bound(target)
}

// ---------- setup: inverse table pslot[v*28+mm] = global P slot ----------
__global__ __launch_bounds__(256) void pslot_kernel(
    const int* __restrict__ in_idx, int* __restrict__ pslot, int N)
{
    const int mm = blockIdx.x;
    const int j0 = blockIdx.y * 256;
    const int* src = in_idx + (size_t)mm * N;
    if (src[j0] >= N) return;                   // padded suffix: whole block skips (prefix property)
    int j = j0 + threadIdx.x;
    if (j >= N) return;
    int v = src[j];                             // destination voxel of this pair
    if (v >= N) return;                         // padded
    if (mm != 13 && j >= CAP) return;           // safety (never triggers)
    int base = (mm == 13) ? 0 : N + ((mm < 13) ? mm : mm - 1) * CAP;
    pslot[(size_t)v * 28 + mm] = base + j;      // 4B random scatter (the only one)
}

// ---------- conv1 phase A: sequential gather + GEMM -> pair buffer ----------
__global__ __launch_bounds__(256) void conv1A_kernel(
    const float* __restrict__ feat, const float* __restrict__ W1,
    const int* __restrict__ out_idx, const int* __restrict__ r,
    float* __restrict__ P, int N, int nwin)
{
    const int mm = blockIdx.x;
    const int b  = blockIdx.y;
    int jlo = r[mm * (nwin + 1) + b];
    int jhi = r[mm * (nwin + 1) + b + 1];
    if (mm != 13 && jhi > CAP) jhi = CAP;       // safety
    if (jlo >= jhi) return;

    __shared__ float Wl[C2 * C1];               // Wl[c*128+i] = W1[k][i][c], k=26-mm
    const int k = 26 - mm;
    const int tid = threadIdx.x;
    for (int t = tid; t < C2 * C1; t += 256) {
        int c = t >> 7, i = t & 127;
        Wl[t] = W1[k * (C1 * C2) + i * C2 + c];
    }
    __syncthreads();

    const int base = (mm == 13) ? 0 : N + ((mm < 13) ? mm : mm - 1) * CAP;
    const int* gidx = out_idx + (size_t)mm * N;

    for (int j = jlo + tid; j < jhi; j += 256) {
        int v = gidx[j];                        // ascending within this 1024-row window
        const float4* f = (const float4*)(feat + (size_t)v * C1);
        float acc[C2];
        #pragma unroll
        for (int c = 0; c < C2; ++c) acc[c] = 0.f;
        for (int i4 = 0; i4 < C1 / 4; ++i4) {
            float4 a = f[i4];
            #pragma unroll
            for (int c = 0; c < C2; ++c) {
                float4 w = *(const float4*)&Wl[c * C1 + i4 * 4];
                acc[c] = fmaf(a.x, w.x, fmaf(a.y, w.y, fmaf(a.z, w.z, fmaf(a.w, w.w, acc[c]))));
            }
        }
        float* p = P + (size_t)(base + j) * PROW;
        float4 o;
        o = make_float4(acc[0], acc[1], acc[2], acc[3]);   *(float4*)(p + 0)  = o;
        o = make_float4(acc[4], acc[5], acc[6], acc[7]);   *(float4*)(p + 4)  = o;
        o = make_float4(acc[8], acc[9], acc[10], acc[11]); *(float4*)(p + 8)  = o;
        o = make_float4(acc[12], acc[13], 0.f, 0.f);       *(float4*)(p + 12) = o;
    }
}

// ---------- conv1 phase B: per-voxel sum of pair rows + GELU -> x1 ----------
__global__ __launch_bounds__(256) void conv1B_kernel(
    const float* __restrict__ P, const int* __restrict__ pslot,
    float* __restrict__ x1, int N)
{
    int v = blockIdx.x * 256 + threadIdx.x;
    if (v >= N) return;
    const int4* ps = (const int4*)(pslot + (size_t)v * 28);
    int s[28];
    #pragma unroll
    for (int q = 0; q < 7; ++q) {
        int4 t = ps[q];
        s[q * 4 + 0] = t.x; s[q * 4 + 1] = t.y; s[q * 4 + 2] = t.z; s[q * 4 + 3] = t.w;
    }
    float acc[C2];
    #pragma unroll
    for (int c = 0; c < C2; ++c) acc[c] = 0.f;
    #pragma unroll
    for (int mm = 0; mm < NK; ++mm) {
        int sl = s[mm];
        if (sl < 0) continue;
        const float4* q = (const float4*)(P + (size_t)sl * PROW);
        float4 a = q[0], b = q[1], c4 = q[2], d = q[3];
        acc[0] += a.x;  acc[1] += a.y;  acc[2] += a.z;  acc[3] += a.w;
        acc[4] += b.x;  acc[5] += b.y;  acc[6] += b.z;  acc[7] += b.w;
        acc[8] += c4.x; acc[9] += c4.y; acc[10] += c4.z; acc[11] += c4.w;
        acc[12] += d.x; acc[13] += d.y;
    }
    #pragma unroll
    for (int c = 0; c < C2; ++c) {
        float x = acc[c];
        acc[c] = 0.5f * x * (1.0f + erff(x * 0.70710678118654752f));
    }
    float* o = x1 + (size_t)v * X1S;
    *(float4*)(o + 0)  = make_float4(acc[0], acc[1], acc[2], acc[3]);
    *(float4*)(o + 4)  = make_float4(acc[4], acc[5], acc[6], acc[7]);
    *(float4*)(o + 8)  = make_float4(acc[8], acc[9], acc[10], acc[11]);
    *(float4*)(o + 12) = make_float4(acc[12], acc[13], 0.f, 0.f);
}

// ---------- conv2 phase A: gather x1 rows + small GEMM -> pair buffer ----------
__global__ __launch_bounds__(256) void conv2A_kernel(
    const float* __restrict__ x1, const float* __restrict__ W2,
    const int* __restrict__ out_idx, const int* __restrict__ r,
    float* __restrict__ P, int N, int nwin)
{
    const int mm = blockIdx.x;
    const int b  = blockIdx.y;
    int jlo = r[mm * (nwin + 1) + b];
    int jhi = r[mm * (nwin + 1) + b + 1];
    if (mm != 13 && jhi > CAP) jhi = CAP;
    if (jlo >= jhi) return;

    __shared__ float Wl[C2 * 16];               // Wl[c*16+i] = W2[k][i][c]
    const int k = 26 - mm;
    const int tid = threadIdx.x;
    if (tid < C2 * C2) {
        int c = tid / C2, i = tid % C2;
        Wl[c * 16 + i] = W2[k * (C2 * C2) + i * C2 + c];
    }
    __syncthreads();

    const int base = (mm == 13) ? 0 : N + ((mm < 13) ? mm : mm - 1) * CAP;
    const int* gidx = out_idx + (size_t)mm * N;

    for (int j = jlo + tid; j < jhi; j += 256) {
        int v = gidx[j];
        const float* rrow = x1 + (size_t)v * X1S;
        float4 q0 = *(const float4*)(rrow + 0);
        float4 q1 = *(const float4*)(rrow + 4);
        float4 q2 = *(const float4*)(rrow + 8);
        float2 q3 = *(const float2*)(rrow + 12);
        float f[C2] = { q0.x,q0.y,q0.z,q0.w, q1.x,q1.y,q1.z,q1.w,
                        q2.x,q2.y,q2.z,q2.w, q3.x,q3.y };
        float acc[C2];
        #pragma unroll
        for (int c = 0; c < C2; ++c) {
            float sum = 0.f;
            #pragma unroll
            for (int i = 0; i < C2; ++i) sum = fmaf(f[i], Wl[c * 16 + i], sum);
            acc[c] = sum;
        }
        float* p = P + (size_t)(base + j) * PROW;
        *(float4*)(p + 0)  = make_float4(acc[0], acc[1], acc[2], acc[3]);
        *(float4*)(p + 4)  = make_float4(acc[4], acc[5], acc[6], acc[7]);
        *(float4*)(p + 8)  = make_float4(acc[8], acc[9], acc[10], acc[11]);
        *(float4*)(p + 12) = make_float4(acc[12], acc[13], 0.f, 0.f);
    }
}

// ---------- conv2 phase B: per-voxel sum -> out (N x 14 packed) ----------
__global__ __launch_bounds__(256) void conv2B_kernel(
    const float* __restrict__ P, const int* __restrict__ pslot,
    float* __restrict__ out, int N)
{
    int v = blockIdx.x * 256 + threadIdx.x;
    if (v >= N) return;
    const int4* ps = (const int4*)(pslot + (size_t)v * 28);
    int s[28];
    #pragma unroll
    for (int q = 0; q < 7; ++q) {
        int4 t = ps[q];
        s[q * 4 + 0] = t.x; s[q * 4 + 1] = t.y; s[q * 4 + 2] = t.z; s[q * 4 + 3] = t.w;
    }
    float acc[C2];
    #pragma unroll
    for (int c = 0; c < C2; ++c) acc[c] = 0.f;
    #pragma unroll
    for (int mm = 0; mm < NK; ++mm) {
        int sl = s[mm];
        if (sl < 0) continue;
        const float4* q = (const float4*)(P + (size_t)sl * PROW);
        float4 a = q[0], b = q[1], c4 = q[2], d = q[3];
        acc[0] += a.x;  acc[1] += a.y;  acc[2] += a.z;  acc[3] += a.w;
        acc[4] += b.x;  acc[5] += b.y;  acc[6] += b.z;  acc[7] += b.w;
        acc[8] += c4.x; acc[9] += c4.y; acc[10] += c4.z; acc[11] += c4.w;
        acc[12] += d.x; acc[13] += d.y;
    }
    float* o = out + (size_t)v * C2;             // 56B rows, 8B aligned
    *(float2*)(o + 0)  = make_float2(acc[0], acc[1]);
    *(float2*)(o + 2)  = make_float2(acc[2], acc[3]);
    *(float2*)(o + 4)  = make_float2(acc[4], acc[5]);
    *(float2*)(o + 6)  = make_float2(acc[6], acc[7]);
    *(float2*)(o + 8)  = make_float2(acc[8], acc[9]);
    *(float2*)(o + 10) = make_float2(acc[10], acc[11]);
    *(float2*)(o + 12) = make_float2(acc[12], acc[13]);
}

// ================= fallback (round-1 path, needs only 25.6MB ws) =================
__global__ __launch_bounds__(256) void fb_conv1_kernel(
    const float* __restrict__ feat, const float* __restrict__ W1,
    const int* __restrict__ in_idx, const int* __restrict__ out_idx,
    float* __restrict__ x1, int N)
{
    __shared__ float Wl[C2 * C1];
    const int k = blockIdx.y;
    const int tid = threadIdx.x;
    for (int t = tid; t < C2 * C1; t += 256) {
        int c = t >> 7, i = t & 127;
        Wl[t] = W1[k * (C1 * C2) + i * C2 + c];
    }
    __syncthreads();
    const int jbase = (blockIdx.x * 256 + tid) * 4;
    if (jbase >= N) return;
    int src[4], dst[4];
    for (int p = 0; p < 4; ++p) {
        int j = jbase + p;
        src[p] = (j < N) ? in_idx[(size_t)k * N + j]  : N;
        dst[p] = (j < N) ? out_idx[(size_t)k * N + j] : N;
    }
    bool valid[4]; bool any = false;
    for (int p = 0; p < 4; ++p) { valid[p] = (dst[p] < N); any |= valid[p]; if (!valid[p]) src[p] = 0; }
    if (!any) return;
    float acc[4][C2];
    for (int p = 0; p < 4; ++p) for (int c = 0; c < C2; ++c) acc[p][c] = 0.f;
    for (int i4 = 0; i4 < C1 / 4; ++i4) {
        float4 a = ((const float4*)(feat + (size_t)src[0] * C1))[i4];
        float4 b = ((const float4*)(feat + (size_t)src[1] * C1))[i4];
        float4 cc = ((const float4*)(feat + (size_t)src[2] * C1))[i4];
        float4 d = ((const float4*)(feat + (size_t)src[3] * C1))[i4];
        for (int c = 0; c < C2; ++c) {
            float4 w = *(const float4*)&Wl[c * C1 + i4 * 4];
            acc[0][c] = fmaf(a.x, w.x, fmaf(a.y, w.y, fmaf(a.z, w.z, fmaf(a.w, w.w, acc[0][c]))));
            acc[1][c] = fmaf(b.x, w.x, fmaf(b.y, w.y, fmaf(b.z, w.z, fmaf(b.w, w.w, acc[1][c]))));
            acc[2][c] = fmaf(cc.x, w.x, fmaf(cc.y, w.y, fmaf(cc.z, w.z, fmaf(cc.w, w.w, acc[2][c]))));
            acc[3][c] = fmaf(d.x, w.x, fmaf(d.y, w.y, fmaf(d.z, w.z, fmaf(d.w, w.w, acc[3][c]))));
        }
    }
    for (int p = 0; p < 4; ++p) {
        if (!valid[p]) continue;
        float* o = x1 + (size_t)dst[p] * X1S;
        for (int c = 0; c < C2; ++c) atomicAdd(o + c, acc[p][c]);
    }
}

__global__ __launch_bounds__(256) void fb_gelu_kernel(float* __restrict__ x, int total4)
{
    int i = blockIdx.x * 256 + threadIdx.x;
    if (i >= total4) return;
    float4 v = ((float4*)x)[i];
    v.x = 0.5f * v.x * (1.0f + erff(v.x * 0.70710678118654752f));
    v.y = 0.5f * v.y * (1.0f + erff(v.y * 0.70710678118654752f));
    v.z = 0.5f * v.z * (1.0f + erff(v.z * 0.70710678118654752f));
    v.w = 0.5f * v.w * (1.0f + erff(v.w * 0.70710678118654752f));
    ((float4*)x)[i] = v;
}

__global__ __launch_bounds__(256) void fb_conv2_kernel(
    const float* __restrict__ x1, const float* __restrict__ W2,
    const int* __restrict__ in_idx, const int* __restrict__ out_idx,
    float* __restrict__ out, int N)
{
    __shared__ float Wl[C2 * 16];
    const int k = blockIdx.y;
    const int tid = threadIdx.x;
    if (tid < C2 * C2) {
        int c = tid / C2, i = tid % C2;
        Wl[c * 16 + i] = W2[k * (C2 * C2) + i * C2 + c];
    }
    __syncthreads();
    const int j = blockIdx.x * 256 + tid;
    if (j >= N) return;
    int src = in_idx[(size_t)k * N + j];
    int dst = out_idx[(size_t)k * N + j];
    if (dst >= N) return;
    const float* rrow = x1 + (size_t)src * X1S;
    float f[C2];
    for (int i = 0; i < C2; ++i) f[i] = rrow[i];
    float* o = out + (size_t)dst * C2;
    for (int c = 0; c < C2; ++c) {
        float sum = 0.f;
        for (int i = 0; i < C2; ++i) sum = fmaf(f[i], Wl[c * 16 + i], sum);
        atomicAdd(o + c, sum);
    }
}

// ================================ launcher ================================
extern "C" void kernel_launch(void* const* d_in, const int* in_sizes, int n_in,
                              void* d_out, int out_size, void* d_ws, size_t ws_size,
                              hipStream_t stream)
{
    const float* feat    = (const float*)d_in[0];
    const float* W1      = (const float*)d_in[1];
    const float* W2      = (const float*)d_in[2];
    const int*   in_idx  = (const int*)d_in[3];
    const int*   out_idx = (const int*)d_in[4];
    float*       out     = (float*)d_out;

    const int N    = in_sizes[0] / C1;               // 400000
    const int nwin = (N + WIN - 1) / WIN;            // 391

    const size_t prows      = (size_t)N + 26ull * CAP;          // 3,807,872
    const size_t p_bytes    = prows * PROW * sizeof(float);     // ~243.7 MB
    const size_t pslot_bytes = (size_t)N * 28 * sizeof(int);    // 44.8 MB
    const size_t x1_bytes   = (size_t)N * X1S * sizeof(float);  // 25.6 MB
    const size_t r_bytes    = (size_t)NK * (nwin + 1) * sizeof(int);
    const size_t need = p_bytes + pslot_bytes + x1_bytes + ((r_bytes + 255) & ~255ull) + 1024;

    if (ws_size >= need) {
        char* w = (char*)d_ws;
        float* P     = (float*)w;                 w += p_bytes;
        int*   pslot = (int*)w;                   w += pslot_bytes;
        float* x1    = (float*)w;                 w += x1_bytes;
        int*   r     = (int*)w;

        hipMemsetAsync(pslot, 0xFF, pslot_bytes, stream);

        int rtot = NK * (nwin + 1);
        ranges_kernel<<<(rtot + 255) / 256, 256, 0, stream>>>(out_idx, r, N, nwin);

        {
            dim3 grid(NK, (N + 255) / 256);
            pslot_kernel<<<grid, 256, 0, stream>>>(in_idx, pslot, N);
        }
        {
            dim3 grid(NK, nwin);
            conv1A_kernel<<<grid, 256, 0, stream>>>(feat, W1, out_idx, r, P, N, nwin);
        }
        conv1B_kernel<<<(N + 255) / 256, 256, 0, stream>>>(P, pslot, x1, N);
        {
            dim3 grid(NK, nwin);
            conv2A_kernel<<<grid, 256, 0, stream>>>(x1, W2, out_idx, r, P, N, nwin);
        }
        conv2B_kernel<<<(N + 255) / 256, 256, 0, stream>>>(P, pslot, out, N);
    } else {
        // fallback: round-1 path (ws needs only 25.6 MB)
        float* x1 = (float*)d_ws;
        hipMemsetAsync(x1, 0, x1_bytes, stream);
        hipMemsetAsync(out, 0, (size_t)out_size * sizeof(float), stream);
        {
            dim3 grid((N + 1023) / 1024, NK);
            fb_conv1_kernel<<<grid, 256, 0, stream>>>(feat, W1, in_idx, out_idx, x1, N);
        }
        {
            int total4 = N * X1S / 4;
            fb_gelu_kernel<<<(total4 + 255) / 256, 256, 0, stream>>>(x1, total4);
        }
        {
            dim3 grid((N + 255) / 256, NK);
            fb_conv2_kernel<<<grid, 256, 0, stream>>>(x1, W2, in_idx, out_idx, out, N);
        }
    }
}